// Round 1
// 100.657 us; speedup vs baseline: 1.0367x; 1.0367x over previous
//
#include <hip/hip_runtime.h>

// B=8, S=1024, D=256, H=16, HD=16. Rows G = B*S = 8192.
#define Gz 8192
#define Dz 256
#define Sz 1024

typedef _Float16 half8  __attribute__((ext_vector_type(8)));
typedef _Float16 half4  __attribute__((ext_vector_type(4)));
typedef _Float16 half2v __attribute__((ext_vector_type(2)));
typedef float    floatx4 __attribute__((ext_vector_type(4)));

// width-16 async global->LDS (wave-uniform base + lane*16 layout required)
#define GLOAD_LDS(gptr, lptr)                                                      \
    __builtin_amdgcn_global_load_lds(                                              \
        (const __attribute__((address_space(1))) void*)(gptr),                     \
        (__attribute__((address_space(3))) void*)(lptr), 16, 0, 0)

__device__ inline half4 cvt4(float4 a) {
    half4 h;
    h[0]=(_Float16)a.x; h[1]=(_Float16)a.y; h[2]=(_Float16)a.z; h[3]=(_Float16)a.w;
    return h;
}

// ---------------------------------------------------------------------------
// K1: C[8192x512] = fp16(x) @ fp16([Wq;Wv])^T, +bias, RoPE -> xq/xv (fp16).
// Fp32->fp16 conversion fused (no separate convert kernel / x16 round-trip).
// Reg-staged LDS with T2 XOR-swizzle (byte ^= (row&7)<<4) on write AND read:
// fixes the 16-way ds_read_b128 bank conflict the global_load_lds path had.
// 128x128 tile, BK=64, 4 waves each 64x64.
// ---------------------------------------------------------------------------
__global__ __launch_bounds__(256) void qv_gemm_rope(
    const float* __restrict__ x, const float* __restrict__ wq,
    const float* __restrict__ wv,
    const float* __restrict__ bq, const float* __restrict__ bv,
    _Float16* __restrict__ xq, _Float16* __restrict__ xv)
{
    __shared__ __align__(16) _Float16 As[128 * 64];
    __shared__ __align__(16) _Float16 Bs[128 * 64];
    const int t = threadIdx.x, lane = t & 63, w = t >> 6;
    const int g0 = blockIdx.x * 128;
    const int by = blockIdx.y;              // 0..3 -> cols [by*128, +128)
    const int wm = (w >> 1) * 64, wn = (w & 1) * 64;
    const int fr = lane & 15, kq = lane >> 4;
    // packed weight rows [0..255]=Wq, [256..511]=Wv; this block's 128 rows:
    const float* wsrc = ((by < 2) ? wq : wv) + (size_t)(by & 1) * 128 * Dz;

    char* Ab = (char*)As;
    char* Bb = (char*)Bs;

    floatx4 acc[4][4] = {};

    for (int k0 = 0; k0 < Dz; k0 += 64) {
        // stage: flat float4 tiling -> each wave instr reads 4 contiguous rows
        float4 a4[8], b4[8];
        #pragma unroll
        for (int p = 0; p < 8; ++p) {
            const int id = t + 256 * p;          // float4 id in 128x64 tile
            const int row = id >> 4, c4 = id & 15;
            a4[p] = *(const float4*)(x    + (size_t)(g0 + row) * Dz + k0 + c4 * 4);
            b4[p] = *(const float4*)(wsrc + (size_t)row        * Dz + k0 + c4 * 4);
        }
        __syncthreads();                         // prev iter's reads done
        #pragma unroll
        for (int p = 0; p < 8; ++p) {
            const int id = t + 256 * p;
            const int row = id >> 4, cb = (id & 15) * 8;      // byte col (fp16)
            const int off = row * 128 + (cb ^ ((row & 7) << 4));
            *(half4*)(Ab + off) = cvt4(a4[p]);
            *(half4*)(Bb + off) = cvt4(b4[p]);
        }
        __syncthreads();
        #pragma unroll
        for (int ks = 0; ks < 2; ++ks) {
            const int kb = (ks * 32 + kq * 8) * 2;            // k byte offset
            half8 a[4], b[4];
            #pragma unroll
            for (int i = 0; i < 4; ++i) {
                const int r = wm + i * 16 + fr;
                a[i] = *(const half8*)(Ab + r * 128 + (kb ^ ((r & 7) << 4)));
            }
            #pragma unroll
            for (int j = 0; j < 4; ++j) {
                const int r = wn + j * 16 + fr;
                b[j] = *(const half8*)(Bb + r * 128 + (kb ^ ((r & 7) << 4)));
            }
            #pragma unroll
            for (int i = 0; i < 4; ++i)
                #pragma unroll
                for (int j = 0; j < 4; ++j)
                    acc[i][j] = __builtin_amdgcn_mfma_f32_16x16x32_f16(a[i], b[j], acc[i][j], 0, 0, 0);
        }
    }

    // Epilogue. C layout: col=lane&15 (n side), row=kq*4+reg (m side).
    // theta is block-uniform: cols of this block sit entirely in one half.
    const int qside = (by < 2);
    const float* bias = qside ? bq : bv;
    _Float16* outp = qside ? xq : xv;
    const float theta = (by & 1) ? 1e-4f : 1.0f;
    const float sign  = (fr & 1) ? 1.0f : -1.0f;

    float sn[4][4], cs[4][4];
    #pragma unroll
    for (int i = 0; i < 4; ++i)
        #pragma unroll
        for (int r = 0; r < 4; ++r) {
            const int g = g0 + wm + i * 16 + kq * 4 + r;
            const float pos = (float)((g & (Sz - 1)) + 1);
            __sincosf(pos * theta, &sn[i][r], &cs[i][r]);
        }

    #pragma unroll
    for (int j = 0; j < 4; ++j) {
        const int ch = (by & 1) * 128 + wn + j * 16 + fr;   // col within 256
        const float bcol = bias[ch];
        #pragma unroll
        for (int i = 0; i < 4; ++i)
            #pragma unroll
            for (int r = 0; r < 4; ++r) {
                const int g = g0 + wm + i * 16 + kq * 4 + r;
                float v = acc[i][j][r] + bcol;
                float other = __shfl_xor(v, 1, 64);   // pair partner col ch^1
                outp[(size_t)g * Dz + ch] =
                    (_Float16)(v * sn[i][r] + sign * other * cs[i][r]);
            }
    }
}

// ---------------------------------------------------------------------------
// K2: fused head_outer + make_p. One block per (b,h), 512 threads.
// Phase A: M[e][f] = sum_{s=0..1023} xq[b,s,h16+e]*xv[b,s,h16+f]
//          (wave-split S, LDS-transposed staging, fdot2 inner product).
// Phase B: Pt[b][c][h16+e] = fp16( 0.25 * sum_f M[e][f]*Wo[c][h16+f] )
//          -- P's column slice [h16,h16+16) depends only on this block's M.
// Removes the Mpart global round-trip and two kernel launches.
// ---------------------------------------------------------------------------
__global__ __launch_bounds__(512) void head_p(
    const _Float16* __restrict__ xq, const _Float16* __restrict__ xv,
    const float* __restrict__ wo, _Float16* __restrict__ Pt)
{
    __shared__ __align__(16) _Float16 qsT[16][264];   // 256 s-cols + pad
    __shared__ __align__(16) _Float16 vsT[16][264];
    __shared__ float red[512];
    __shared__ float Ms[256];

    const int t = threadIdx.x;
    const int bh = blockIdx.x;
    const int b = bh >> 4, h = bh & 15;
    const size_t base = (size_t)b * Sz * Dz + h * 16;

    const int s  = t >> 1, eg = t & 1;           // staging role
    const int e  = (t >> 4) & 15, f = t & 15;    // compute role
    const int hf = t >> 8;                       // which 128-s half of strip

    float acc = 0.f;
    for (int it = 0; it < 4; ++it) {
        const size_t roff = base + (size_t)(it * 256 + s) * Dz + eg * 8;
        half8 q8 = *(const half8*)&xq[roff];     // issue before barrier
        half8 v8 = *(const half8*)&xv[roff];
        __syncthreads();                         // prev strip fully consumed
        #pragma unroll
        for (int i = 0; i < 8; ++i) {
            qsT[eg * 8 + i][s] = q8[i];
            vsT[eg * 8 + i][s] = v8[i];
        }
        __syncthreads();
        #pragma unroll
        for (int s0 = 0; s0 < 128; s0 += 8) {
            half8 q = *(const half8*)&qsT[e][hf * 128 + s0];
            half8 v = *(const half8*)&vsT[f][hf * 128 + s0];
#if __has_builtin(__builtin_amdgcn_fdot2)
            #pragma unroll
            for (int k = 0; k < 4; ++k) {
                half2v a2 = {q[2*k], q[2*k+1]};
                half2v b2 = {v[2*k], v[2*k+1]};
                acc = __builtin_amdgcn_fdot2(a2, b2, acc, false);
            }
#else
            #pragma unroll
            for (int k = 0; k < 8; ++k) acc += (float)q[k] * (float)v[k];
#endif
        }
    }
    red[t] = acc;
    __syncthreads();
    if (t < 256) Ms[t] = (red[t] + red[t + 256]) * 0.25f;   // M[e*16+f], scaled
    __syncthreads();

    // Phase B: thread (c = t>>1, e-half = t&1) -> 8 outputs of 16-fma dots.
    const int c = t >> 1;
    float wv_[16];
    const float4* wop = (const float4*)&wo[(size_t)c * Dz + h * 16];
    #pragma unroll
    for (int q4 = 0; q4 < 4; ++q4) {
        float4 v4 = wop[q4];
        wv_[4*q4+0] = v4.x; wv_[4*q4+1] = v4.y; wv_[4*q4+2] = v4.z; wv_[4*q4+3] = v4.w;
    }
    half8 r;
    #pragma unroll
    for (int ee = 0; ee < 8; ++ee) {
        const int e_ = eg * 8 + ee;
        float a = 0.f;
        #pragma unroll
        for (int ff = 0; ff < 16; ++ff) a = fmaf(Ms[e_ * 16 + ff], wv_[ff], a);
        r[ee] = (_Float16)a;
    }
    *(half8*)&Pt[((size_t)(b * 256 + c)) * Dz + h * 16 + eg * 8] = r;
}

// ---------------------------------------------------------------------------
// K3: out[g][c] = sum_r xq16[g][r] * Pt[b][c][r] + bo[c], fp32 out.
// 64x128 tile, BK=64, grid (128,2) = 256 blocks. Waves each 32x64. Unchanged.
// ---------------------------------------------------------------------------
__global__ __launch_bounds__(256) void out_gemm(
    const _Float16* __restrict__ xq, const _Float16* __restrict__ Pt,
    const float* __restrict__ bo, float* __restrict__ out)
{
    __shared__ _Float16 As[64 * 64];
    __shared__ _Float16 Bs[128 * 64];
    const int t = threadIdx.x, lane = t & 63, w = t >> 6;
    const int g0 = blockIdx.x * 64;
    const int n0 = blockIdx.y * 128;
    const int b  = g0 >> 10;
    const int wm = (w >> 1) * 32, wn = (w & 1) * 64;
    const int fr = lane & 15, kq = lane >> 4;
    const _Float16* Pb = Pt + (size_t)b * 256 * Dz;

    floatx4 acc[2][4] = {};

    for (int k0 = 0; k0 < Dz; k0 += 64) {
        __syncthreads();
        #pragma unroll
        for (int p = 0; p < 2; ++p) {
            const int flat = (t + 256 * p) * 8;
            const int row = flat >> 6, col = flat & 63;
            GLOAD_LDS(xq + (size_t)(g0 + row) * Dz + k0 + col, &As[flat]);
        }
        #pragma unroll
        for (int p = 0; p < 4; ++p) {
            const int flat = (t + 256 * p) * 8;
            const int row = flat >> 6, col = flat & 63;
            GLOAD_LDS(Pb + (size_t)(n0 + row) * Dz + k0 + col, &Bs[flat]);
        }
        __syncthreads();
        #pragma unroll
        for (int ks = 0; ks < 2; ++ks) {
            const int kk = ks * 32 + kq * 8;
            half8 a[2], bf[4];
            #pragma unroll
            for (int i = 0; i < 2; ++i) a[i] = *(const half8*)&As[(wm + i * 16 + fr) * 64 + kk];
            #pragma unroll
            for (int j = 0; j < 4; ++j) bf[j] = *(const half8*)&Bs[(wn + j * 16 + fr) * 64 + kk];
            #pragma unroll
            for (int i = 0; i < 2; ++i)
                #pragma unroll
                for (int j = 0; j < 4; ++j)
                    acc[i][j] = __builtin_amdgcn_mfma_f32_16x16x32_f16(a[i], bf[j], acc[i][j], 0, 0, 0);
        }
    }

    #pragma unroll
    for (int j = 0; j < 4; ++j) {
        const int c = n0 + wn + j * 16 + fr;
        const float bcol = bo[c];
        #pragma unroll
        for (int i = 0; i < 2; ++i)
            #pragma unroll
            for (int r = 0; r < 4; ++r) {
                const int g = g0 + wm + i * 16 + kq * 4 + r;
                out[(size_t)g * Dz + c] = acc[i][j][r] + bcol;
            }
    }
}

// ---------------------------------------------------------------------------
extern "C" void kernel_launch(void* const* d_in, const int* in_sizes, int n_in,
                              void* d_out, int out_size, void* d_ws, size_t ws_size,
                              hipStream_t stream)
{
    const float* x    = (const float*)d_in[0];
    const float* wq_w = (const float*)d_in[1];
    const float* wq_b = (const float*)d_in[2];
    // d_in[3], d_in[4] = wk_w, wk_b : dead in the no-cache reference path
    const float* wv_w = (const float*)d_in[5];
    const float* wv_b = (const float*)d_in[6];
    const float* wo_w = (const float*)d_in[7];
    const float* wo_b = (const float*)d_in[8];

    _Float16* xq16 = (_Float16*)d_ws;                    // 2M halfs
    _Float16* xv16 = xq16 + (size_t)Gz * Dz;             // 2M halfs
    _Float16* Pt   = xv16 + (size_t)Gz * Dz;             // 524288 halfs
    float*    out  = (float*)d_out;

    qv_gemm_rope<<<dim3(Gz / 128, 4), 256, 0, stream>>>(
        x, wq_w, wv_w, wq_b, wv_b, xq16, xv16);
    head_p<<<dim3(128), 512, 0, stream>>>(xq16, xv16, wo_w, Pt);
    out_gemm<<<dim3(Gz / 64, 2), 256, 0, stream>>>(xq16, Pt, wo_b, out);
}

// Round 3
// 97.176 us; speedup vs baseline: 1.0738x; 1.0358x over previous
//
#include <hip/hip_runtime.h>

// B=8, S=1024, D=256, H=16, HD=16. Rows G = B*S = 8192.
#define Gz 8192
#define Dz 256
#define Sz 1024

typedef _Float16 half8  __attribute__((ext_vector_type(8)));
typedef _Float16 half4  __attribute__((ext_vector_type(4)));
typedef _Float16 half2v __attribute__((ext_vector_type(2)));
typedef float    floatx4 __attribute__((ext_vector_type(4)));

// width-16 async global->LDS (wave-uniform base + lane*16 layout required)
#define GLOAD_LDS(gptr, lptr)                                                      \
    __builtin_amdgcn_global_load_lds(                                              \
        (const __attribute__((address_space(1))) void*)(gptr),                     \
        (__attribute__((address_space(3))) void*)(lptr), 16, 0, 0)

__device__ inline half4 cvt4(float4 a) {
    half4 h;
    h[0]=(_Float16)a.x; h[1]=(_Float16)a.y; h[2]=(_Float16)a.z; h[3]=(_Float16)a.w;
    return h;
}

// ---------------------------------------------------------------------------
// K1: C[8192x512] = fp16(x) @ fp16([Wq;Wv])^T, +bias, RoPE -> xq/xv (fp16).
// 128x64 tiles -> 512 blocks = 2 blocks/CU (was 1/CU: latency-exposed).
// Reg-staged LDS with T2 XOR-swizzle (byte ^= (row&7)<<4) on write AND read.
// 4 waves each 64x32.
// ---------------------------------------------------------------------------
__global__ __launch_bounds__(256, 2) void qv_gemm_rope(
    const float* __restrict__ x, const float* __restrict__ wq,
    const float* __restrict__ wv,
    const float* __restrict__ bq, const float* __restrict__ bv,
    _Float16* __restrict__ xq, _Float16* __restrict__ xv)
{
    __shared__ __align__(16) _Float16 As[128 * 64];   // 16 KB
    __shared__ __align__(16) _Float16 Bs[64 * 64];    // 8 KB
    const int t = threadIdx.x, lane = t & 63, w = t >> 6;
    const int g0 = blockIdx.x * 128;
    const int by = blockIdx.y;              // 0..7 -> 64-col strips of [Q|V]
    const int wm = (w >> 1) * 64, wn = (w & 1) * 32;
    const int fr = lane & 15, kq = lane >> 4;
    // packed weight rows [0..255]=Wq, [256..511]=Wv; this block's 64 rows:
    const float* wsrc = ((by < 4) ? wq : wv) + (size_t)(by & 3) * 64 * Dz;

    char* Ab = (char*)As;
    char* Bb = (char*)Bs;

    floatx4 acc[4][2] = {};

    for (int k0 = 0; k0 < Dz; k0 += 64) {
        // stage to regs first (T14: issue loads before the barrier)
        float4 a4[8], b4[4];
        #pragma unroll
        for (int p = 0; p < 8; ++p) {
            const int id = t + 256 * p;          // float4 id in 128x64 tile
            const int row = id >> 4, c4 = id & 15;
            a4[p] = *(const float4*)(x + (size_t)(g0 + row) * Dz + k0 + c4 * 4);
        }
        #pragma unroll
        for (int p = 0; p < 4; ++p) {
            const int id = t + 256 * p;          // float4 id in 64x64 tile
            const int row = id >> 4, c4 = id & 15;
            b4[p] = *(const float4*)(wsrc + (size_t)row * Dz + k0 + c4 * 4);
        }
        __syncthreads();                         // prev iter's reads done
        #pragma unroll
        for (int p = 0; p < 8; ++p) {
            const int id = t + 256 * p;
            const int row = id >> 4, cb = (id & 15) * 8;      // byte col
            *(half4*)(Ab + row * 128 + (cb ^ ((row & 7) << 4))) = cvt4(a4[p]);
        }
        #pragma unroll
        for (int p = 0; p < 4; ++p) {
            const int id = t + 256 * p;
            const int row = id >> 4, cb = (id & 15) * 8;
            *(half4*)(Bb + row * 128 + (cb ^ ((row & 7) << 4))) = cvt4(b4[p]);
        }
        __syncthreads();
        #pragma unroll
        for (int ks = 0; ks < 2; ++ks) {
            const int kb = (ks * 32 + kq * 8) * 2;            // k byte offset
            half8 a[4], b[2];
            #pragma unroll
            for (int i = 0; i < 4; ++i) {
                const int r = wm + i * 16 + fr;
                a[i] = *(const half8*)(Ab + r * 128 + (kb ^ ((r & 7) << 4)));
            }
            #pragma unroll
            for (int j = 0; j < 2; ++j) {
                const int r = wn + j * 16 + fr;
                b[j] = *(const half8*)(Bb + r * 128 + (kb ^ ((r & 7) << 4)));
            }
            #pragma unroll
            for (int i = 0; i < 4; ++i)
                #pragma unroll
                for (int j = 0; j < 2; ++j)
                    acc[i][j] = __builtin_amdgcn_mfma_f32_16x16x32_f16(a[i], b[j], acc[i][j], 0, 0, 0);
        }
    }

    // Epilogue. C layout: col=lane&15 (n side), row=kq*4+reg (m side).
    // theta is block-uniform: this 64-col strip sits entirely in one half.
    const int qside = (by < 4);
    const float* bias = qside ? bq : bv;
    _Float16* outp = qside ? xq : xv;
    const float theta = (by & 2) ? 1e-4f : 1.0f;
    const float sign  = (fr & 1) ? 1.0f : -1.0f;

    float sn[4][4], cs[4][4];
    #pragma unroll
    for (int i = 0; i < 4; ++i)
        #pragma unroll
        for (int r = 0; r < 4; ++r) {
            const int g = g0 + wm + i * 16 + kq * 4 + r;
            const float pos = (float)((g & (Sz - 1)) + 1);
            __sincosf(pos * theta, &sn[i][r], &cs[i][r]);
        }

    #pragma unroll
    for (int j = 0; j < 2; ++j) {
        const int ch = (by & 3) * 64 + wn + j * 16 + fr;   // col within 256
        const float bcol = bias[ch];
        #pragma unroll
        for (int i = 0; i < 4; ++i)
            #pragma unroll
            for (int r = 0; r < 4; ++r) {
                const int g = g0 + wm + i * 16 + kq * 4 + r;
                float v = acc[i][j][r] + bcol;
                float other = __shfl_xor(v, 1, 64);   // pair partner col ch^1
                outp[(size_t)g * Dz + ch] =
                    (_Float16)(v * sn[i][r] + sign * other * cs[i][r]);
            }
    }
}

// ---------------------------------------------------------------------------
// K2: fused head_outer + make_p. One block per (b,h), 512 threads.
// Phase A: M[e][f] = sum_{s=0..1023} xq[b,s,h16+e]*xv[b,s,h16+f]
// Phase B: Pt[b][c][h16+e] = fp16( 0.25 * sum_f M[e][f]*Wo[c][h16+f] )
// ---------------------------------------------------------------------------
__global__ __launch_bounds__(512) void head_p(
    const _Float16* __restrict__ xq, const _Float16* __restrict__ xv,
    const float* __restrict__ wo, _Float16* __restrict__ Pt)
{
    __shared__ __align__(16) _Float16 qsT[16][264];   // 256 s-cols + pad
    __shared__ __align__(16) _Float16 vsT[16][264];
    __shared__ float red[512];
    __shared__ float Ms[256];

    const int t = threadIdx.x;
    const int bh = blockIdx.x;
    const int b = bh >> 4, h = bh & 15;
    const size_t base = (size_t)b * Sz * Dz + h * 16;

    const int s  = t >> 1, eg = t & 1;           // staging role
    const int e  = (t >> 4) & 15, f = t & 15;    // compute role
    const int hf = t >> 8;                       // which 128-s half of strip

    float acc = 0.f;
    for (int it = 0; it < 4; ++it) {
        const size_t roff = base + (size_t)(it * 256 + s) * Dz + eg * 8;
        half8 q8 = *(const half8*)&xq[roff];     // issue before barrier
        half8 v8 = *(const half8*)&xv[roff];
        __syncthreads();                         // prev strip fully consumed
        #pragma unroll
        for (int i = 0; i < 8; ++i) {
            qsT[eg * 8 + i][s] = q8[i];
            vsT[eg * 8 + i][s] = v8[i];
        }
        __syncthreads();
        #pragma unroll
        for (int s0 = 0; s0 < 128; s0 += 8) {
            half8 q = *(const half8*)&qsT[e][hf * 128 + s0];
            half8 v = *(const half8*)&vsT[f][hf * 128 + s0];
#if __has_builtin(__builtin_amdgcn_fdot2)
            #pragma unroll
            for (int k = 0; k < 4; ++k) {
                half2v a2 = {q[2*k], q[2*k+1]};
                half2v b2 = {v[2*k], v[2*k+1]};
                acc = __builtin_amdgcn_fdot2(a2, b2, acc, false);
            }
#else
            #pragma unroll
            for (int k = 0; k < 8; ++k) acc += (float)q[k] * (float)v[k];
#endif
        }
    }
    red[t] = acc;
    __syncthreads();
    if (t < 256) Ms[t] = (red[t] + red[t + 256]) * 0.25f;   // M[e*16+f], scaled
    __syncthreads();

    // Phase B: thread (c = t>>1, e-half = t&1) -> 8 outputs of 16-fma dots.
    const int c = t >> 1;
    float wv_[16];
    const float4* wop = (const float4*)&wo[(size_t)c * Dz + h * 16];
    #pragma unroll
    for (int q4 = 0; q4 < 4; ++q4) {
        float4 v4 = wop[q4];
        wv_[4*q4+0] = v4.x; wv_[4*q4+1] = v4.y; wv_[4*q4+2] = v4.z; wv_[4*q4+3] = v4.w;
    }
    half8 r;
    #pragma unroll
    for (int ee = 0; ee < 8; ++ee) {
        const int e_ = eg * 8 + ee;
        float a = 0.f;
        #pragma unroll
        for (int ff = 0; ff < 16; ++ff) a = fmaf(Ms[e_ * 16 + ff], wv_[ff], a);
        r[ee] = (_Float16)a;
    }
    *(half8*)&Pt[((size_t)(b * 256 + c)) * Dz + h * 16 + eg * 8] = r;
}

// ---------------------------------------------------------------------------
// K3: out[g][c] = sum_r xq16[g][r] * Pt[b][c][r] + bo[c], fp32 out.
// 64x64 tiles -> grid (128,4) = 512 blocks = 2/CU. Waves each 32x32.
// Bank-conflict fix via PRE-SWIZZLED global source (m201/s09): the 16B
// column-chunk index is XORed with (row&7) on the global address; LDS dest
// stays linear (global_load_lds requirement); ds_read applies the same XOR.
// ---------------------------------------------------------------------------
__global__ __launch_bounds__(256, 2) void out_gemm(
    const _Float16* __restrict__ xq, const _Float16* __restrict__ Pt,
    const float* __restrict__ bo, float* __restrict__ out)
{
    __shared__ __align__(16) _Float16 As[64 * 64];    // 8 KB
    __shared__ __align__(16) _Float16 Bs[64 * 64];    // 8 KB
    const int t = threadIdx.x, lane = t & 63, w = t >> 6;
    const int g0 = blockIdx.x * 64;
    const int n0 = blockIdx.y * 64;
    const int b  = g0 >> 10;
    const int wm = (w >> 1) * 32, wn = (w & 1) * 32;
    const int fr = lane & 15, kq = lane >> 4;
    const _Float16* Pb = Pt + (size_t)b * 256 * Dz;

    char* Ab = (char*)As;
    char* Bb = (char*)Bs;

    floatx4 acc[2][2] = {};

    for (int k0 = 0; k0 < Dz; k0 += 64) {
        __syncthreads();
        #pragma unroll
        for (int p = 0; p < 2; ++p) {
            const int flat = (t + 256 * p) * 8;               // half index
            const int row = flat >> 6, ch = (flat >> 3) & 7;  // 16B chunk
            const int scol = (ch ^ (row & 7)) * 8;            // swizzled src
            GLOAD_LDS(xq + (size_t)(g0 + row) * Dz + k0 + scol, &As[flat]);
        }
        #pragma unroll
        for (int p = 0; p < 2; ++p) {
            const int flat = (t + 256 * p) * 8;
            const int row = flat >> 6, ch = (flat >> 3) & 7;
            const int scol = (ch ^ (row & 7)) * 8;
            GLOAD_LDS(Pb + (size_t)(n0 + row) * Dz + k0 + scol, &Bs[flat]);
        }
        __syncthreads();
        #pragma unroll
        for (int ks = 0; ks < 2; ++ks) {
            const int kb = (ks * 32 + kq * 8) * 2;            // k byte offset
            half8 a[2], bf[2];
            #pragma unroll
            for (int i = 0; i < 2; ++i) {
                const int r = wm + i * 16 + fr;
                a[i] = *(const half8*)(Ab + r * 128 + (kb ^ ((r & 7) << 4)));
            }
            #pragma unroll
            for (int j = 0; j < 2; ++j) {
                const int r = wn + j * 16 + fr;
                bf[j] = *(const half8*)(Bb + r * 128 + (kb ^ ((r & 7) << 4)));
            }
            #pragma unroll
            for (int i = 0; i < 2; ++i)
                #pragma unroll
                for (int j = 0; j < 2; ++j)
                    acc[i][j] = __builtin_amdgcn_mfma_f32_16x16x32_f16(a[i], bf[j], acc[i][j], 0, 0, 0);
        }
    }

    #pragma unroll
    for (int j = 0; j < 2; ++j) {
        const int c = n0 + wn + j * 16 + fr;
        const float bcol = bo[c];
        #pragma unroll
        for (int i = 0; i < 2; ++i)
            #pragma unroll
            for (int r = 0; r < 4; ++r) {
                const int g = g0 + wm + i * 16 + kq * 4 + r;
                out[(size_t)g * Dz + c] = acc[i][j][r] + bcol;
            }
    }
}

// ---------------------------------------------------------------------------
extern "C" void kernel_launch(void* const* d_in, const int* in_sizes, int n_in,
                              void* d_out, int out_size, void* d_ws, size_t ws_size,
                              hipStream_t stream)
{
    const float* x    = (const float*)d_in[0];
    const float* wq_w = (const float*)d_in[1];
    const float* wq_b = (const float*)d_in[2];
    // d_in[3], d_in[4] = wk_w, wk_b : dead in the no-cache reference path
    const float* wv_w = (const float*)d_in[5];
    const float* wv_b = (const float*)d_in[6];
    const float* wo_w = (const float*)d_in[7];
    const float* wo_b = (const float*)d_in[8];

    _Float16* xq16 = (_Float16*)d_ws;                    // 2M halfs
    _Float16* xv16 = xq16 + (size_t)Gz * Dz;             // 2M halfs
    _Float16* Pt   = xv16 + (size_t)Gz * Dz;             // 524288 halfs
    float*    out  = (float*)d_out;

    qv_gemm_rope<<<dim3(Gz / 128, 8), 256, 0, stream>>>(
        x, wq_w, wv_w, wq_b, wv_b, xq16, xv16);
    head_p<<<dim3(128), 512, 0, stream>>>(xq16, xv16, wo_w, Pt);
    out_gemm<<<dim3(Gz / 64, 4), 256, 0, stream>>>(xq16, Pt, wo_b, out);
}